// Round 21
// baseline (46.841 us; speedup 1.0000x reference)
//
#include <hip/hip_runtime.h>

// Laplacian3D: R17 structure EXACTLY (10-slot full-plane LDS ring, named
// register z-ring, counted vmcnt, paired-step barriers = 17), single change:
// NORMAL stores instead of nontemporal. NT bypasses L2/L3 -> store bursts hit
// HBM raw; cached stores retire into L2/L3 write-back, which smooths the
// burst into steady drain. A/B on the store path; everything else untouched.

#define NSLOT 10
#define PLANEF 4096   // 64*64 floats = 16 KB
#define CHUNK 32

typedef float fx4 __attribute__((ext_vector_type(4)));

#define GLD(gsrc, ldst) __builtin_amdgcn_global_load_lds(                      \
    (const __attribute__((address_space(1))) unsigned int*)(gsrc),             \
    (__attribute__((address_space(3))) unsigned int*)(ldst), 16, 0, 0)

#define VMW(N) asm volatile("s_waitcnt vmcnt(" #N ")" ::: "memory")

#define F4E(v, j) ((j) == 0 ? (v).x : (j) == 1 ? (v).y : (j) == 2 ? (v).z : (v).w)

// One z-step. A0 = plane Z0+IZ-4 on entry, Z0+IZ+4 on exit (ring fill).
// NW = vmcnt immediate (63 = no-op), HG = issue GLD(z+8), BR = barrier after.
#define STEP(Z0, IZ, NW, HG, BR, A0, A1, A2, A3, A4, A5, A6, A7)               \
  {                                                                            \
    if (HG)                                                                    \
        GLD(vol + (size_t)((Z0) + (IZ) + 8) * PLANEF + foff,                   \
            &lds[((Z0) + (IZ) + 8) % NSLOT][wbase]);                           \
    VMW(NW);                                                                   \
    const float4 zm4 = A0;                                                     \
    A0 = ((Z0) + (IZ) + 4 < 64)                                                \
         ? *(const float4*)(&lds[((Z0) + (IZ) + 4) % NSLOT][foff]) : zero;     \
    const float4 zp4 = A0;                                                     \
    const float4 zm2 = A2, zm1 = A3, ctr = A4, zp1 = A5, zp2 = A6;             \
    const float* plz = &lds[((Z0) + (IZ)) % NSLOT][0];                         \
    const float4 wm = *(const float4*)(plz + wmoff);                           \
    const float4 wp = *(const float4*)(plz + wpoff);                           \
    const float4 ym4t = *(const float4*)(plz + yoff[0]);                       \
    const float4 ym2t = *(const float4*)(plz + yoff[1]);                       \
    const float4 ym1t = *(const float4*)(plz + yoff[2]);                       \
    const float4 yp1t = *(const float4*)(plz + yoff[3]);                       \
    const float4 yp2t = *(const float4*)(plz + yoff[4]);                       \
    const float4 yp4t = *(const float4*)(plz + yoff[5]);                       \
    const float win[12] = {wm.x * wmm, wm.y * wmm, wm.z * wmm, wm.w * wmm,     \
                           ctr.x, ctr.y, ctr.z, ctr.w,                         \
                           wp.x * wpm, wp.y * wpm, wp.z * wpm, wp.w * wpm};    \
    fx4 o;                                                                     \
    _Pragma("unroll")                                                          \
    for (int j = 0; j < 4; ++j) {                                              \
        const float s1 = F4E(zm1, j) + F4E(zp1, j) + win[3 + j] + win[5 + j]   \
                       + ym[2] * F4E(ym1t, j) + ym[3] * F4E(yp1t, j);          \
        const float s2 = F4E(zm2, j) + F4E(zp2, j) + win[2 + j] + win[6 + j]   \
                       + ym[1] * F4E(ym2t, j) + ym[4] * F4E(yp2t, j);          \
        const float s4 = F4E(zm4, j) + F4E(zp4, j) + win[j] + win[8 + j]       \
                       + ym[0] * F4E(ym4t, j) + ym[5] * F4E(yp4t, j);          \
        o[j] = km6 * win[4 + j] + k1 * s1 + k2 * s2 + k4 * s4;                 \
    }                                                                          \
    *(fx4*)(ovol + (size_t)((Z0) + (IZ)) * PLANEF + foff) = o;                 \
    if (BR) __builtin_amdgcn_s_barrier();                                      \
  }

// rotation wrappers (ring period 8)
#define S0(Z0,IZ,NW,HG,BR) STEP(Z0,IZ,NW,HG,BR, a0,a1,a2,a3,a4,a5,a6,a7)
#define S1(Z0,IZ,NW,HG,BR) STEP(Z0,IZ,NW,HG,BR, a1,a2,a3,a4,a5,a6,a7,a0)
#define S2(Z0,IZ,NW,HG,BR) STEP(Z0,IZ,NW,HG,BR, a2,a3,a4,a5,a6,a7,a0,a1)
#define S3(Z0,IZ,NW,HG,BR) STEP(Z0,IZ,NW,HG,BR, a3,a4,a5,a6,a7,a0,a1,a2)
#define S4(Z0,IZ,NW,HG,BR) STEP(Z0,IZ,NW,HG,BR, a4,a5,a6,a7,a0,a1,a2,a3)
#define S5(Z0,IZ,NW,HG,BR) STEP(Z0,IZ,NW,HG,BR, a5,a6,a7,a0,a1,a2,a3,a4)
#define S6(Z0,IZ,NW,HG,BR) STEP(Z0,IZ,NW,HG,BR, a6,a7,a0,a1,a2,a3,a4,a5)
#define S7(Z0,IZ,NW,HG,BR) STEP(Z0,IZ,NW,HG,BR, a7,a0,a1,a2,a3,a4,a5,a6)

// prologue: ring-init reg loads (planes Z0-4..Z0+3), 8 GLDs (Z0..Z0+7),
// VMW(4) (planes Z0..Z0+3 landed -> step-0/1 taps safe via prologue barrier).
#define PROLOGUE(Z0)                                                           \
    float4 a0, a1, a2, a3, a4, a5, a6, a7;                                     \
    {                                                                          \
        float4* rr[8] = {&a0, &a1, &a2, &a3, &a4, &a5, &a6, &a7};              \
        _Pragma("unroll")                                                      \
        for (int i = 0; i < 8; ++i)                                            \
            *rr[i] = ((Z0) - 4 + i >= 0)                                       \
                ? *(const float4*)(vol + (size_t)((Z0) - 4 + i) * PLANEF + foff) \
                : zero;                                                        \
    }                                                                          \
    _Pragma("unroll")                                                          \
    for (int i = 0; i < 8; ++i)                                                \
        GLD(vol + (size_t)((Z0) + i) * PLANEF + foff,                          \
            &lds[((Z0) + i) % NSLOT][wbase]);                                  \
    VMW(4);                                                                    \
    __builtin_amdgcn_s_barrier();

__global__ __launch_bounds__(1024) void lap3d_cst(
    const float* __restrict__ x, const float* __restrict__ p,
    float* __restrict__ out)
{
    __shared__ __align__(16) float lds[NSLOT][PLANEF];   // 163840 B

    const int tid   = threadIdx.x;
    const int bc    = blockIdx.x & 127;       // b*64 + c
    const int chunk = blockIdx.x >> 7;        // chunk pairs 128 apart: same XCD
    const int c     = bc & 63;

    const float* vol  = x   + (size_t)bc * (64 * PLANEF);
    float*       ovol = out + (size_t)bc * (64 * PLANEF);

    const int y     = tid >> 4;
    const int w0    = (tid & 15) << 2;
    const int foff  = tid << 2;               // y*64 + w0
    const int wbase = (tid >> 6) << 8;        // wave's float base in a plane

    const float k1  = 0.25f / (1.0f + __expf(-p[c]));
    const float k2  = 0.25f / (1.0f + __expf(-p[64 + c]));
    const float k4  = 0.25f / (1.0f + __expf(-p[128 + c]));
    const float km6 = -6.0f * (k1 + k2 + k4);

    // y-tap clamped offsets + masks
    const int dys[6] = {-4, -2, -1, 1, 2, 4};
    int yoff[6]; float ym[6];
#pragma unroll
    for (int k = 0; k < 6; ++k) {
        const int yy = y + dys[k];
        const bool v = (unsigned)yy < 64u;
        yoff[k] = (v ? yy : y) * 64 + w0;
        ym[k]   = v ? 1.0f : 0.0f;
    }
    // w-tap clamped offsets + masks (quad-aligned)
    const bool  wmv = (w0 >= 4), wpv = (w0 <= 56);
    const int   wmoff = wmv ? foff - 4 : foff;
    const int   wpoff = wpv ? foff + 4 : foff;
    const float wmm = wmv ? 1.0f : 0.0f, wpm = wpv ? 1.0f : 0.0f;

    const float4 zero = make_float4(0.f, 0.f, 0.f, 0.f);

    if (chunk == 0) {
        PROLOGUE(0)
        S0(0, 0,4,1,0)  S1(0, 1,5,1,1)  S2(0, 2,6,1,0)  S3(0, 3,7,1,1)
        S4(0, 4,8,1,0)  S5(0, 5,8,1,1)  S6(0, 6,8,1,0)  S7(0, 7,8,1,1)
        S0(0, 8,8,1,0)  S1(0, 9,8,1,1)  S2(0,10,8,1,0)  S3(0,11,8,1,1)
        S4(0,12,8,1,0)  S5(0,13,8,1,1)  S6(0,14,8,1,0)  S7(0,15,8,1,1)
        S0(0,16,8,1,0)  S1(0,17,8,1,1)  S2(0,18,8,1,0)  S3(0,19,8,1,1)
        S4(0,20,8,1,0)  S5(0,21,8,1,1)  S6(0,22,8,1,0)  S7(0,23,8,1,1)
        S0(0,24,8,1,0)  S1(0,25,8,1,1)  S2(0,26,8,1,0)  S3(0,27,8,1,1)
        S4(0,28,7,0,0)  S5(0,29,6,0,1)  S6(0,30,5,0,0)  S7(0,31,4,0,0)
    } else {
        PROLOGUE(32)
        S0(32, 0,4,1,0)  S1(32, 1,5,1,1)  S2(32, 2,6,1,0)  S3(32, 3,7,1,1)
        S4(32, 4,8,1,0)  S5(32, 5,8,1,1)  S6(32, 6,8,1,0)  S7(32, 7,8,1,1)
        S0(32, 8,8,1,0)  S1(32, 9,8,1,1)  S2(32,10,8,1,0)  S3(32,11,8,1,1)
        S4(32,12,8,1,0)  S5(32,13,8,1,1)  S6(32,14,8,1,0)  S7(32,15,8,1,1)
        S0(32,16,8,1,0)  S1(32,17,8,1,1)  S2(32,18,8,1,0)  S3(32,19,8,1,1)
        S4(32,20,8,1,0)  S5(32,21,8,1,1)  S6(32,22,8,1,0)  S7(32,23,8,1,1)
        S0(32,24,7,0,0)  S1(32,25,6,0,1)  S2(32,26,5,0,0)  S3(32,27,4,0,1)
        S4(32,28,63,0,0) S5(32,29,63,0,1) S6(32,30,63,0,0) S7(32,31,63,0,0)
    }
}

extern "C" void kernel_launch(void* const* d_in, const int* in_sizes, int n_in,
                              void* d_out, int out_size, void* d_ws, size_t ws_size,
                              hipStream_t stream) {
    const float* x = (const float*)d_in[0];
    const float* p = (const float*)d_in[1];
    float* out = (float*)d_out;
    lap3d_cst<<<256, 1024, 0, stream>>>(x, p, out);
}

// Round 22
// 44.579 us; speedup vs baseline: 1.0507x; 1.0507x over previous
//
#include <hip/hip_runtime.h>

// Laplacian3D — FINAL (R17 structure, best measured: 44.77 us).
// 10-slot full-plane LDS ring (160 KiB) + named-register z-ring + counted
// vmcnt (never 0 in steady state) + paired-step raw barriers (17 total).
// Prefetch distance 8 (GLD(z+8) -> slot of plane z-2, ordered by the
// inter-pair barrier); steady VMW(8) = 4-step pipeline slack; nontemporal
// stores (A/B'd vs cached: NT is 2.1 us faster). Ladder: naive 100 ->
// LDS ring 58.7 -> prefetch-before-compute 50.1 -> counted vmcnt 47.3 ->
// paired barriers 44.8. Refuted levers: zero-barrier (halo traffic),
// 4-step groups (slack loss), DPP w-taps (DS not limiting), cached stores,
// 2/4 barrier domains, deferred stores. d+g<=10 closes the design space.

#define NSLOT 10
#define PLANEF 4096   // 64*64 floats = 16 KB
#define CHUNK 32

typedef float fx4 __attribute__((ext_vector_type(4)));

#define GLD(gsrc, ldst) __builtin_amdgcn_global_load_lds(                      \
    (const __attribute__((address_space(1))) unsigned int*)(gsrc),             \
    (__attribute__((address_space(3))) unsigned int*)(ldst), 16, 0, 0)

#define VMW(N) asm volatile("s_waitcnt vmcnt(" #N ")" ::: "memory")

#define F4E(v, j) ((j) == 0 ? (v).x : (j) == 1 ? (v).y : (j) == 2 ? (v).z : (v).w)

// One z-step. A0 = plane Z0+IZ-4 on entry, Z0+IZ+4 on exit (ring fill).
// NW = vmcnt immediate (63 = no-op), HG = issue GLD(z+8), BR = barrier after.
#define STEP(Z0, IZ, NW, HG, BR, A0, A1, A2, A3, A4, A5, A6, A7)               \
  {                                                                            \
    if (HG)                                                                    \
        GLD(vol + (size_t)((Z0) + (IZ) + 8) * PLANEF + foff,                   \
            &lds[((Z0) + (IZ) + 8) % NSLOT][wbase]);                           \
    VMW(NW);                                                                   \
    const float4 zm4 = A0;                                                     \
    A0 = ((Z0) + (IZ) + 4 < 64)                                                \
         ? *(const float4*)(&lds[((Z0) + (IZ) + 4) % NSLOT][foff]) : zero;     \
    const float4 zp4 = A0;                                                     \
    const float4 zm2 = A2, zm1 = A3, ctr = A4, zp1 = A5, zp2 = A6;             \
    const float* plz = &lds[((Z0) + (IZ)) % NSLOT][0];                         \
    const float4 wm = *(const float4*)(plz + wmoff);                           \
    const float4 wp = *(const float4*)(plz + wpoff);                           \
    const float4 ym4t = *(const float4*)(plz + yoff[0]);                       \
    const float4 ym2t = *(const float4*)(plz + yoff[1]);                       \
    const float4 ym1t = *(const float4*)(plz + yoff[2]);                       \
    const float4 yp1t = *(const float4*)(plz + yoff[3]);                       \
    const float4 yp2t = *(const float4*)(plz + yoff[4]);                       \
    const float4 yp4t = *(const float4*)(plz + yoff[5]);                       \
    const float win[12] = {wm.x * wmm, wm.y * wmm, wm.z * wmm, wm.w * wmm,     \
                           ctr.x, ctr.y, ctr.z, ctr.w,                         \
                           wp.x * wpm, wp.y * wpm, wp.z * wpm, wp.w * wpm};    \
    fx4 o;                                                                     \
    _Pragma("unroll")                                                          \
    for (int j = 0; j < 4; ++j) {                                              \
        const float s1 = F4E(zm1, j) + F4E(zp1, j) + win[3 + j] + win[5 + j]   \
                       + ym[2] * F4E(ym1t, j) + ym[3] * F4E(yp1t, j);          \
        const float s2 = F4E(zm2, j) + F4E(zp2, j) + win[2 + j] + win[6 + j]   \
                       + ym[1] * F4E(ym2t, j) + ym[4] * F4E(yp2t, j);          \
        const float s4 = F4E(zm4, j) + F4E(zp4, j) + win[j] + win[8 + j]       \
                       + ym[0] * F4E(ym4t, j) + ym[5] * F4E(yp4t, j);          \
        o[j] = km6 * win[4 + j] + k1 * s1 + k2 * s2 + k4 * s4;                 \
    }                                                                          \
    __builtin_nontemporal_store(                                               \
        o, (fx4*)(ovol + (size_t)((Z0) + (IZ)) * PLANEF + foff));              \
    if (BR) __builtin_amdgcn_s_barrier();                                      \
  }

// rotation wrappers (ring period 8)
#define S0(Z0,IZ,NW,HG,BR) STEP(Z0,IZ,NW,HG,BR, a0,a1,a2,a3,a4,a5,a6,a7)
#define S1(Z0,IZ,NW,HG,BR) STEP(Z0,IZ,NW,HG,BR, a1,a2,a3,a4,a5,a6,a7,a0)
#define S2(Z0,IZ,NW,HG,BR) STEP(Z0,IZ,NW,HG,BR, a2,a3,a4,a5,a6,a7,a0,a1)
#define S3(Z0,IZ,NW,HG,BR) STEP(Z0,IZ,NW,HG,BR, a3,a4,a5,a6,a7,a0,a1,a2)
#define S4(Z0,IZ,NW,HG,BR) STEP(Z0,IZ,NW,HG,BR, a4,a5,a6,a7,a0,a1,a2,a3)
#define S5(Z0,IZ,NW,HG,BR) STEP(Z0,IZ,NW,HG,BR, a5,a6,a7,a0,a1,a2,a3,a4)
#define S6(Z0,IZ,NW,HG,BR) STEP(Z0,IZ,NW,HG,BR, a6,a7,a0,a1,a2,a3,a4,a5)
#define S7(Z0,IZ,NW,HG,BR) STEP(Z0,IZ,NW,HG,BR, a7,a0,a1,a2,a3,a4,a5,a6)

// prologue: ring-init reg loads (planes Z0-4..Z0+3), 8 GLDs (Z0..Z0+7),
// VMW(4) (planes Z0..Z0+3 landed -> step-0/1 taps safe via prologue barrier).
#define PROLOGUE(Z0)                                                           \
    float4 a0, a1, a2, a3, a4, a5, a6, a7;                                     \
    {                                                                          \
        float4* rr[8] = {&a0, &a1, &a2, &a3, &a4, &a5, &a6, &a7};              \
        _Pragma("unroll")                                                      \
        for (int i = 0; i < 8; ++i)                                            \
            *rr[i] = ((Z0) - 4 + i >= 0)                                       \
                ? *(const float4*)(vol + (size_t)((Z0) - 4 + i) * PLANEF + foff) \
                : zero;                                                        \
    }                                                                          \
    _Pragma("unroll")                                                          \
    for (int i = 0; i < 8; ++i)                                                \
        GLD(vol + (size_t)((Z0) + i) * PLANEF + foff,                          \
            &lds[((Z0) + i) % NSLOT][wbase]);                                  \
    VMW(4);                                                                    \
    __builtin_amdgcn_s_barrier();

__global__ __launch_bounds__(1024) void lap3d_final(
    const float* __restrict__ x, const float* __restrict__ p,
    float* __restrict__ out)
{
    __shared__ __align__(16) float lds[NSLOT][PLANEF];   // 163840 B

    const int tid   = threadIdx.x;
    const int bc    = blockIdx.x & 127;       // b*64 + c
    const int chunk = blockIdx.x >> 7;        // chunk pairs 128 apart: same XCD
    const int c     = bc & 63;

    const float* vol  = x   + (size_t)bc * (64 * PLANEF);
    float*       ovol = out + (size_t)bc * (64 * PLANEF);

    const int y     = tid >> 4;
    const int w0    = (tid & 15) << 2;
    const int foff  = tid << 2;               // y*64 + w0
    const int wbase = (tid >> 6) << 8;        // wave's float base in a plane

    const float k1  = 0.25f / (1.0f + __expf(-p[c]));
    const float k2  = 0.25f / (1.0f + __expf(-p[64 + c]));
    const float k4  = 0.25f / (1.0f + __expf(-p[128 + c]));
    const float km6 = -6.0f * (k1 + k2 + k4);

    // y-tap clamped offsets + masks
    const int dys[6] = {-4, -2, -1, 1, 2, 4};
    int yoff[6]; float ym[6];
#pragma unroll
    for (int k = 0; k < 6; ++k) {
        const int yy = y + dys[k];
        const bool v = (unsigned)yy < 64u;
        yoff[k] = (v ? yy : y) * 64 + w0;
        ym[k]   = v ? 1.0f : 0.0f;
    }
    // w-tap clamped offsets + masks (quad-aligned)
    const bool  wmv = (w0 >= 4), wpv = (w0 <= 56);
    const int   wmoff = wmv ? foff - 4 : foff;
    const int   wpoff = wpv ? foff + 4 : foff;
    const float wmm = wmv ? 1.0f : 0.0f, wpm = wpv ? 1.0f : 0.0f;

    const float4 zero = make_float4(0.f, 0.f, 0.f, 0.f);

    if (chunk == 0) {
        PROLOGUE(0)
        S0(0, 0,4,1,0)  S1(0, 1,5,1,1)  S2(0, 2,6,1,0)  S3(0, 3,7,1,1)
        S4(0, 4,8,1,0)  S5(0, 5,8,1,1)  S6(0, 6,8,1,0)  S7(0, 7,8,1,1)
        S0(0, 8,8,1,0)  S1(0, 9,8,1,1)  S2(0,10,8,1,0)  S3(0,11,8,1,1)
        S4(0,12,8,1,0)  S5(0,13,8,1,1)  S6(0,14,8,1,0)  S7(0,15,8,1,1)
        S0(0,16,8,1,0)  S1(0,17,8,1,1)  S2(0,18,8,1,0)  S3(0,19,8,1,1)
        S4(0,20,8,1,0)  S5(0,21,8,1,1)  S6(0,22,8,1,0)  S7(0,23,8,1,1)
        S0(0,24,8,1,0)  S1(0,25,8,1,1)  S2(0,26,8,1,0)  S3(0,27,8,1,1)
        S4(0,28,7,0,0)  S5(0,29,6,0,1)  S6(0,30,5,0,0)  S7(0,31,4,0,0)
    } else {
        PROLOGUE(32)
        S0(32, 0,4,1,0)  S1(32, 1,5,1,1)  S2(32, 2,6,1,0)  S3(32, 3,7,1,1)
        S4(32, 4,8,1,0)  S5(32, 5,8,1,1)  S6(32, 6,8,1,0)  S7(32, 7,8,1,1)
        S0(32, 8,8,1,0)  S1(32, 9,8,1,1)  S2(32,10,8,1,0)  S3(32,11,8,1,1)
        S4(32,12,8,1,0)  S5(32,13,8,1,1)  S6(32,14,8,1,0)  S7(32,15,8,1,1)
        S0(32,16,8,1,0)  S1(32,17,8,1,1)  S2(32,18,8,1,0)  S3(32,19,8,1,1)
        S4(32,20,8,1,0)  S5(32,21,8,1,1)  S6(32,22,8,1,0)  S7(32,23,8,1,1)
        S0(32,24,7,0,0)  S1(32,25,6,0,1)  S2(32,26,5,0,0)  S3(32,27,4,0,1)
        S4(32,28,63,0,0) S5(32,29,63,0,1) S6(32,30,63,0,0) S7(32,31,63,0,0)
    }
}

extern "C" void kernel_launch(void* const* d_in, const int* in_sizes, int n_in,
                              void* d_out, int out_size, void* d_ws, size_t ws_size,
                              hipStream_t stream) {
    const float* x = (const float*)d_in[0];
    const float* p = (const float*)d_in[1];
    float* out = (float*)d_out;
    lap3d_final<<<256, 1024, 0, stream>>>(x, p, out);
}